// Round 7
// baseline (371.061 us; speedup 1.0000x reference)
//
#include <hip/hip_runtime.h>

#define NN 50000
#define NE 800000
#define D  64
#define TILE 64
#define TPB 512
#define NBLK 196   // ceil(NN/256)

// ---------------- CSR build ----------------

__global__ __launch_bounds__(256) void k_count(const int* __restrict__ ei, int* __restrict__ deg) {
    int e = blockIdx.x * 256 + threadIdx.x;
    if (e < NE) atomicAdd(&deg[ei[NE + e]], 1);
}

__global__ __launch_bounds__(256) void k_bsum(const int* __restrict__ deg, int* __restrict__ bsum) {
    __shared__ int s[256];
    int t = threadIdx.x;
    int i = blockIdx.x * 256 + t;
    s[t] = (i < NN) ? deg[i] : 0;
    __syncthreads();
    for (int off = 128; off > 0; off >>= 1) {
        if (t < off) s[t] += s[t + off];
        __syncthreads();
    }
    if (t == 0) bsum[blockIdx.x] = s[0];
}

// per-block exclusive scan + inline block-offset (reads bsum[0..b)) -> row_ptr, cursor
__global__ __launch_bounds__(256) void k_scan2(const int* __restrict__ deg,
                                               const int* __restrict__ bsum,
                                               int* __restrict__ row_ptr,
                                               int* __restrict__ cursor) {
    __shared__ int s[256];
    __shared__ int sboff;
    int t = threadIdx.x;
    int b = blockIdx.x;

    // block offset = sum bsum[0..b)
    int pacc = 0;
    for (int i = t; i < b; i += 256) pacc += bsum[i];
    s[t] = pacc;
    __syncthreads();
    for (int off = 128; off > 0; off >>= 1) {
        if (t < off) s[t] += s[t + off];
        __syncthreads();
    }
    if (t == 0) sboff = s[0];
    __syncthreads();
    int boffv = sboff;
    __syncthreads();           // s[] about to be reused

    int i = b * 256 + t;
    int v = (i < NN) ? deg[i] : 0;
    s[t] = v;
    __syncthreads();
    for (int off = 1; off < 256; off <<= 1) {
        int u = (t >= off) ? s[t - off] : 0;
        __syncthreads();
        s[t] += u;
        __syncthreads();
    }
    int excl = s[t] - v + boffv;
    if (i < NN) { row_ptr[i] = excl; cursor[i] = excl; }
    if (b == 0 && t == 0) row_ptr[NN] = NE;
}

__global__ __launch_bounds__(256) void k_fill(const int* __restrict__ ei,
                                              int* __restrict__ cursor,
                                              int* __restrict__ colv) {
    int e = blockIdx.x * 256 + threadIdx.x;
    if (e < NE) {
        int d = ei[NE + e];
        int p = atomicAdd(&cursor[d], 1);
        colv[p] = ei[e];
    }
}

// ---------------- gather helper (device inline; proven codegen) ----------------

__device__ __forceinline__ float4 gather_row(const float4* __restrict__ h4,
                                             const int* __restrict__ row_ptr,
                                             const int* __restrict__ colv,
                                             int n, int g, int q) {
    float4 a0 = make_float4(0.f, 0.f, 0.f, 0.f);
    float4 a1 = make_float4(0.f, 0.f, 0.f, 0.f);
    float4 a2 = make_float4(0.f, 0.f, 0.f, 0.f);
    float4 a3 = make_float4(0.f, 0.f, 0.f, 0.f);
    if (n >= 0) {
        if (g == 0) a0 = h4[n * 16 + q];           // self term
        int e1 = row_ptr[n + 1];
        int e  = row_ptr[n] + g;
        for (; e + 12 < e1; e += 16) {
            int s0 = colv[e], s1 = colv[e + 4], s2 = colv[e + 8], s3 = colv[e + 12];
            float4 v0 = h4[s0 * 16 + q];
            float4 v1 = h4[s1 * 16 + q];
            float4 v2 = h4[s2 * 16 + q];
            float4 v3 = h4[s3 * 16 + q];
            a0.x += v0.x; a0.y += v0.y; a0.z += v0.z; a0.w += v0.w;
            a1.x += v1.x; a1.y += v1.y; a1.z += v1.z; a1.w += v1.w;
            a2.x += v2.x; a2.y += v2.y; a2.z += v2.z; a2.w += v2.w;
            a3.x += v3.x; a3.y += v3.y; a3.z += v3.z; a3.w += v3.w;
        }
        for (; e < e1; e += 4) {
            float4 v = h4[colv[e] * 16 + q];
            a1.x += v.x; a1.y += v.y; a1.z += v.z; a1.w += v.w;
        }
        a0.x += a1.x + a2.x + a3.x;
        a0.y += a1.y + a2.y + a3.y;
        a0.z += a1.z + a2.z + a3.z;
        a0.w += a1.w + a2.w + a3.w;
    }
    // combine the 4 groups (wave-uniform control)
    a0.x += __shfl_xor(a0.x, 16); a0.y += __shfl_xor(a0.y, 16);
    a0.z += __shfl_xor(a0.z, 16); a0.w += __shfl_xor(a0.w, 16);
    a0.x += __shfl_xor(a0.x, 32); a0.y += __shfl_xor(a0.y, 32);
    a0.z += __shfl_xor(a0.z, 32); a0.w += __shfl_xor(a0.w, 32);
    return a0;
}

// ---------------- fused GIN conv: out = MLP(h + sum h[src]) ----------------
// h1 kept in registers; layer-2 input broadcast via intra-group shuffle.
// LDS = 16K(sW) + 17K(sZ) + 0.5K = 33.5 KB -> 4 blocks/CU; VGPR pinned <= 64.

__global__ __launch_bounds__(TPB, 8) void k_conv(
    const float4* __restrict__ h4,
    const int* __restrict__ row_ptr,
    const int* __restrict__ colv,
    const float* __restrict__ W1, const float* __restrict__ b1,
    const float* __restrict__ W2, const float* __restrict__ b2,
    float4* __restrict__ out4)
{
    __shared__ float sW[D][D];         // W1 then W2
    __shared__ float4 sZ4[TILE][17];   // z (read-only after gather)
    __shared__ float sB1[D], sB2[D];

    int tid = threadIdx.x;
    int node0 = blockIdx.x * TILE;

    {
        const float4* w14 = (const float4*)W1;
        float4* s14 = (float4*)sW;
        for (int i = tid; i < D * D / 4; i += TPB) s14[i] = w14[i];
        if (tid < D) { sB1[tid] = b1[tid]; sB2[tid] = b2[tid]; }
    }

    int wave = tid >> 6, lane = tid & 63;
    int g = lane >> 4, q = lane & 15;

    for (int r = wave; r < TILE; r += (TPB / 64)) {
        int n = node0 + r;
        float4 a = gather_row(h4, row_ptr, colv, (n < NN) ? n : -1, g, q);
        if (g == 0) sZ4[r][q] = a;
    }
    __syncthreads();    // covers W1 preload + gather

    int tr = tid >> 4, tc = tid & 15;
    int segbase = (lane >> 4) << 4;    // first lane of this 16-lane group
    const float* zr0 = (const float*)&sZ4[tr * 2 + 0][0];
    const float* zr1 = (const float*)&sZ4[tr * 2 + 1][0];

    // layer 1 -> registers (relu'd)
    float acc[2][4];
    #pragma unroll
    for (int c = 0; c < 4; ++c) { acc[0][c] = sB1[tc * 4 + c]; acc[1][c] = sB1[tc * 4 + c]; }
    #pragma unroll 16
    for (int k = 0; k < D; ++k) {
        float z0 = zr0[k], z1 = zr1[k];
        #pragma unroll
        for (int c = 0; c < 4; ++c) {
            float w = sW[k][tc * 4 + c];
            acc[0][c] += z0 * w;
            acc[1][c] += z1 * w;
        }
    }
    float hr0[4], hr1[4];
    #pragma unroll
    for (int c = 0; c < 4; ++c) {
        hr0[c] = fmaxf(acc[0][c], 0.f);
        hr1[c] = fmaxf(acc[1][c], 0.f);
    }
    __syncthreads();    // all layer-1 reads of sW done

    {
        const float4* w24 = (const float4*)W2;
        float4* s24 = (float4*)sW;
        for (int i = tid; i < D * D / 4; i += TPB) s24[i] = w24[i];
    }
    __syncthreads();    // W2 visible

    // layer 2: h1[k] broadcast from owning lane via shuffle
    #pragma unroll
    for (int c = 0; c < 4; ++c) { acc[0][c] = sB2[tc * 4 + c]; acc[1][c] = sB2[tc * 4 + c]; }
    #pragma unroll 16
    for (int k = 0; k < D; ++k) {
        int src = segbase + (k >> 2);
        float h0b = __shfl(hr0[k & 3], src);
        float h1b = __shfl(hr1[k & 3], src);
        #pragma unroll
        for (int c = 0; c < 4; ++c) {
            float w = sW[k][tc * 4 + c];
            acc[0][c] += h0b * w;
            acc[1][c] += h1b * w;
        }
    }
    #pragma unroll
    for (int i = 0; i < 2; ++i) {
        int n = node0 + tr * 2 + i;
        if (n < NN) {
            float4 o;
            o.x = acc[i][0]; o.y = acc[i][1]; o.z = acc[i][2]; o.w = acc[i][3];
            out4[n * 16 + tc] = o;
        }
    }
}

// ---------------- one gather of x, three MLPs (params 0/1/2) ----------------
// Same shuffle trick: no sH buffer. LDS = 16K + 17K + 0.25K = 33.3 KB -> 4 blocks/CU.

__global__ __launch_bounds__(TPB, 8) void k_aggmlp3(
    const float4* __restrict__ h4,
    const int* __restrict__ row_ptr,
    const int* __restrict__ colv,
    const float* __restrict__ W1a, const float* __restrict__ b1a,
    const float* __restrict__ W2a, const float* __restrict__ b2a,
    const float* __restrict__ W1b, const float* __restrict__ b1b,
    const float* __restrict__ W2b, const float* __restrict__ b2b,
    const float* __restrict__ W1c, const float* __restrict__ b1c,
    const float* __restrict__ W2c, const float* __restrict__ b2c,
    float4* __restrict__ outA, float4* __restrict__ outB, float4* __restrict__ outC)
{
    __shared__ float sW[D][D];          // 16 KB, reloaded per layer
    __shared__ float4 sZ4[TILE][17];    // z = x + agg (preserved, read-only)
    __shared__ float sB[D];

    int tid = threadIdx.x;
    int node0 = blockIdx.x * TILE;

    int wave = tid >> 6, lane = tid & 63;
    int g = lane >> 4, q = lane & 15;

    for (int r = wave; r < TILE; r += (TPB / 64)) {
        int n = node0 + r;
        float4 a = gather_row(h4, row_ptr, colv, (n < NN) ? n : -1, g, q);
        if (g == 0) sZ4[r][q] = a;
    }

    int tr = tid >> 4, tc = tid & 15;
    int segbase = (lane >> 4) << 4;
    const float* zr0 = (const float*)&sZ4[tr * 2 + 0][0];
    const float* zr1 = (const float*)&sZ4[tr * 2 + 1][0];

    #pragma unroll 1
    for (int m = 0; m < 3; ++m) {
        const float* W1 = (m == 0) ? W1a : (m == 1) ? W1b : W1c;
        const float* B1 = (m == 0) ? b1a : (m == 1) ? b1b : b1c;
        const float* W2 = (m == 0) ? W2a : (m == 1) ? W2b : W2c;
        const float* B2 = (m == 0) ? b2a : (m == 1) ? b2b : b2c;
        float4* out4 = (m == 0) ? outA : (m == 1) ? outB : outC;

        // load W1, b1 (first iteration's sync also covers the gather)
        {
            const float4* w4 = (const float4*)W1;
            float4* s4 = (float4*)sW;
            for (int i = tid; i < D * D / 4; i += TPB) s4[i] = w4[i];
            if (tid < D) sB[tid] = B1[tid];
        }
        __syncthreads();

        float acc[2][4];
        #pragma unroll
        for (int c = 0; c < 4; ++c) { acc[0][c] = sB[tc * 4 + c]; acc[1][c] = sB[tc * 4 + c]; }
        #pragma unroll 16
        for (int k = 0; k < D; ++k) {
            float z0 = zr0[k], z1 = zr1[k];
            #pragma unroll
            for (int c = 0; c < 4; ++c) {
                float w = sW[k][tc * 4 + c];
                acc[0][c] += z0 * w;
                acc[1][c] += z1 * w;
            }
        }
        float hr0[4], hr1[4];
        #pragma unroll
        for (int c = 0; c < 4; ++c) {
            hr0[c] = fmaxf(acc[0][c], 0.f);
            hr1[c] = fmaxf(acc[1][c], 0.f);
        }
        __syncthreads();   // layer-1 reads of sW done

        // load W2, b2
        {
            const float4* w4 = (const float4*)W2;
            float4* s4 = (float4*)sW;
            for (int i = tid; i < D * D / 4; i += TPB) s4[i] = w4[i];
            if (tid < D) sB[tid] = B2[tid];
        }
        __syncthreads();

        #pragma unroll
        for (int c = 0; c < 4; ++c) { acc[0][c] = sB[tc * 4 + c]; acc[1][c] = sB[tc * 4 + c]; }
        #pragma unroll 16
        for (int k = 0; k < D; ++k) {
            int src = segbase + (k >> 2);
            float h0b = __shfl(hr0[k & 3], src);
            float h1b = __shfl(hr1[k & 3], src);
            #pragma unroll
            for (int c = 0; c < 4; ++c) {
                float w = sW[k][tc * 4 + c];
                acc[0][c] += h0b * w;
                acc[1][c] += h1b * w;
            }
        }
        #pragma unroll
        for (int i = 0; i < 2; ++i) {
            int n = node0 + tr * 2 + i;
            if (n < NN) {
                float4 o;
                o.x = acc[i][0]; o.y = acc[i][1]; o.z = acc[i][2]; o.w = acc[i][3];
                out4[n * 16 + tc] = o;
            }
        }
        __syncthreads();   // protect sW/sB before next MLP's load
    }
}

// ---------------- final projection, chunked: out = bo + sum_c Hc @ Wo[c] ----------------

__global__ __launch_bounds__(TPB, 8) void k_final(
    const float4* __restrict__ H0, const float4* __restrict__ H1,
    const float4* __restrict__ H2,
    const float* __restrict__ Wo, const float* __restrict__ bo,
    float4* __restrict__ out4)
{
    __shared__ float sW[D][D];         // one 64x64 chunk of Wo at a time
    __shared__ float4 sY4[TILE][17];   // one 64-feature slice of [H0|H1|H2]
    __shared__ float sB[D];

    int tid = threadIdx.x;
    int node0 = blockIdx.x * TILE;
    int tr = tid >> 4, tc = tid & 15;
    const float* yr0 = (const float*)&sY4[tr * 2 + 0][0];
    const float* yr1 = (const float*)&sY4[tr * 2 + 1][0];

    float accO[2][4];

    #pragma unroll 1
    for (int m = 0; m < 3; ++m) {
        const float4* Hc = (m == 0) ? H0 : (m == 1) ? H1 : H2;
        {
            const float4* w4 = (const float4*)(Wo + m * 64 * D);
            float4* s4 = (float4*)sW;
            for (int i = tid; i < D * D / 4; i += TPB) s4[i] = w4[i];
            if (m == 0 && tid < D) sB[tid] = bo[tid];
        }
        for (int i = tid; i < TILE * 16; i += TPB) {
            int r = i >> 4, qq = i & 15;
            int n = node0 + r;
            sY4[r][qq] = (n < NN) ? Hc[n * 16 + qq] : make_float4(0.f, 0.f, 0.f, 0.f);
        }
        __syncthreads();

        if (m == 0) {
            #pragma unroll
            for (int c = 0; c < 4; ++c) { accO[0][c] = sB[tc * 4 + c]; accO[1][c] = sB[tc * 4 + c]; }
        }
        #pragma unroll 16
        for (int k = 0; k < D; ++k) {
            float z0 = yr0[k], z1 = yr1[k];
            #pragma unroll
            for (int c = 0; c < 4; ++c) {
                float w = sW[k][tc * 4 + c];
                accO[0][c] += z0 * w;
                accO[1][c] += z1 * w;
            }
        }
        __syncthreads();   // before next chunk overwrites sW/sY
    }

    #pragma unroll
    for (int i = 0; i < 2; ++i) {
        int n = node0 + tr * 2 + i;
        if (n < NN) {
            float4 o;
            o.x = accO[i][0]; o.y = accO[i][1]; o.z = accO[i][2]; o.w = accO[i][3];
            out4[n * 16 + tc] = o;
        }
    }
}

// ---------------- launch ----------------

extern "C" void kernel_launch(void* const* d_in, const int* in_sizes, int n_in,
                              void* d_out, int out_size, void* d_ws, size_t ws_size,
                              hipStream_t stream) {
    const float* x    = (const float*)d_in[0];
    const int*   ei   = (const int*)d_in[1];   // [2, NE] int32
    const float* W1_0 = (const float*)d_in[2];
    const float* b1_0 = (const float*)d_in[3];
    const float* W2_0 = (const float*)d_in[4];
    const float* b2_0 = (const float*)d_in[5];
    const float* W1_1 = (const float*)d_in[6];
    const float* b1_1 = (const float*)d_in[7];
    const float* W2_1 = (const float*)d_in[8];
    const float* b2_1 = (const float*)d_in[9];
    const float* W1_2 = (const float*)d_in[10];
    const float* b1_2 = (const float*)d_in[11];
    const float* W2_2 = (const float*)d_in[12];
    const float* b2_2 = (const float*)d_in[13];
    const float* Wo   = (const float*)d_in[14];
    const float* bo   = (const float*)d_in[15];
    float4* out = (float4*)d_out;

    char* ws = (char*)d_ws;
    int* deg     = (int*)(ws + 0);
    int* cursor  = (int*)(ws + 200704);
    int* row_ptr = (int*)(ws + 401408);
    int* colv    = (int*)(ws + 602112);
    int* bsum    = (int*)(ws + 3802112);
    float* fbase = (float*)(ws + 3804160);
    float4* H0  = (float4*)(fbase);
    float4* H1  = (float4*)(fbase + 3200000);
    float4* tB  = (float4*)(fbase + 6400000);   // later reused as H2
    float4* tC2 = (float4*)(fbase + 9600000);
    const float4* x4 = (const float4*)x;

    // CSR build
    hipMemsetAsync(deg, 0, NN * sizeof(int), stream);
    k_count<<<(NE + 255) / 256, 256, 0, stream>>>(ei, deg);
    k_bsum <<<NBLK, 256, 0, stream>>>(deg, bsum);
    k_scan2<<<NBLK, 256, 0, stream>>>(deg, bsum, row_ptr, cursor);
    k_fill <<<(NE + 255) / 256, 256, 0, stream>>>(ei, cursor, colv);

    int nb = (NN + TILE - 1) / TILE;  // 782

    // one gather of x, three MLPs: H0 = f0(x), tB = f1(x), out = f2(x)
    k_aggmlp3<<<nb, TPB, 0, stream>>>(x4, row_ptr, colv,
                                      W1_0, b1_0, W2_0, b2_0,
                                      W1_1, b1_1, W2_1, b2_1,
                                      W1_2, b1_2, W2_2, b2_2,
                                      H0, tB, out);

    // hop-2 tail: H1 = f1(tB)
    k_conv<<<nb, TPB, 0, stream>>>((const float4*)tB, row_ptr, colv,
                                   W1_1, b1_1, W2_1, b2_1, H1);

    // hop-3: tC2 = f2(out); H2 (tB reused) = f2(tC2)
    k_conv<<<nb, TPB, 0, stream>>>((const float4*)out, row_ptr, colv,
                                   W1_2, b1_2, W2_2, b2_2, tC2);
    k_conv<<<nb, TPB, 0, stream>>>((const float4*)tC2, row_ptr, colv,
                                   W1_2, b1_2, W2_2, b2_2, tB);

    // final projection
    k_final<<<nb, TPB, 0, stream>>>((const float4*)H0, (const float4*)H1, (const float4*)tB,
                                    Wo, bo, out);
}

// Round 8
// 342.595 us; speedup vs baseline: 1.0831x; 1.0831x over previous
//
#include <hip/hip_runtime.h>

#define NN 50000
#define NE 800000
#define D  64
#define TILE 64
#define TPB 512
#define NBLK 196   // ceil(NN/256)

// ---------------- CSR build ----------------

__global__ __launch_bounds__(256) void k_count(const int* __restrict__ ei, int* __restrict__ deg) {
    int e = blockIdx.x * 256 + threadIdx.x;
    if (e < NE) atomicAdd(&deg[ei[NE + e]], 1);
}

__global__ __launch_bounds__(256) void k_bsum(const int* __restrict__ deg, int* __restrict__ bsum) {
    __shared__ int s[256];
    int t = threadIdx.x;
    int i = blockIdx.x * 256 + t;
    s[t] = (i < NN) ? deg[i] : 0;
    __syncthreads();
    for (int off = 128; off > 0; off >>= 1) {
        if (t < off) s[t] += s[t + off];
        __syncthreads();
    }
    if (t == 0) bsum[blockIdx.x] = s[0];
}

// per-block exclusive scan + inline block-offset (reads bsum[0..b)) -> row_ptr, cursor
__global__ __launch_bounds__(256) void k_scan2(const int* __restrict__ deg,
                                               const int* __restrict__ bsum,
                                               int* __restrict__ row_ptr,
                                               int* __restrict__ cursor) {
    __shared__ int s[256];
    __shared__ int sboff;
    int t = threadIdx.x;
    int b = blockIdx.x;

    int pacc = 0;
    for (int i = t; i < b; i += 256) pacc += bsum[i];
    s[t] = pacc;
    __syncthreads();
    for (int off = 128; off > 0; off >>= 1) {
        if (t < off) s[t] += s[t + off];
        __syncthreads();
    }
    if (t == 0) sboff = s[0];
    __syncthreads();
    int boffv = sboff;
    __syncthreads();           // s[] about to be reused

    int i = b * 256 + t;
    int v = (i < NN) ? deg[i] : 0;
    s[t] = v;
    __syncthreads();
    for (int off = 1; off < 256; off <<= 1) {
        int u = (t >= off) ? s[t - off] : 0;
        __syncthreads();
        s[t] += u;
        __syncthreads();
    }
    int excl = s[t] - v + boffv;
    if (i < NN) { row_ptr[i] = excl; cursor[i] = excl; }
    if (b == 0 && t == 0) row_ptr[NN] = NE;
}

__global__ __launch_bounds__(256) void k_fill(const int* __restrict__ ei,
                                              int* __restrict__ cursor,
                                              int* __restrict__ colv) {
    int e = blockIdx.x * 256 + threadIdx.x;
    if (e < NE) {
        int d = ei[NE + e];
        int p = atomicAdd(&cursor[d], 1);
        colv[p] = ei[e];
    }
}

// ---------------- gather helper (device inline; proven codegen) ----------------

__device__ __forceinline__ float4 gather_row(const float4* __restrict__ h4,
                                             const int* __restrict__ row_ptr,
                                             const int* __restrict__ colv,
                                             int n, int g, int q) {
    float4 a0 = make_float4(0.f, 0.f, 0.f, 0.f);
    float4 a1 = make_float4(0.f, 0.f, 0.f, 0.f);
    float4 a2 = make_float4(0.f, 0.f, 0.f, 0.f);
    float4 a3 = make_float4(0.f, 0.f, 0.f, 0.f);
    if (n >= 0) {
        if (g == 0) a0 = h4[n * 16 + q];           // self term
        int e1 = row_ptr[n + 1];
        int e  = row_ptr[n] + g;
        for (; e + 12 < e1; e += 16) {
            int s0 = colv[e], s1 = colv[e + 4], s2 = colv[e + 8], s3 = colv[e + 12];
            float4 v0 = h4[s0 * 16 + q];
            float4 v1 = h4[s1 * 16 + q];
            float4 v2 = h4[s2 * 16 + q];
            float4 v3 = h4[s3 * 16 + q];
            a0.x += v0.x; a0.y += v0.y; a0.z += v0.z; a0.w += v0.w;
            a1.x += v1.x; a1.y += v1.y; a1.z += v1.z; a1.w += v1.w;
            a2.x += v2.x; a2.y += v2.y; a2.z += v2.z; a2.w += v2.w;
            a3.x += v3.x; a3.y += v3.y; a3.z += v3.z; a3.w += v3.w;
        }
        for (; e < e1; e += 4) {
            float4 v = h4[colv[e] * 16 + q];
            a1.x += v.x; a1.y += v.y; a1.z += v.z; a1.w += v.w;
        }
        a0.x += a1.x + a2.x + a3.x;
        a0.y += a1.y + a2.y + a3.y;
        a0.z += a1.z + a2.z + a3.z;
        a0.w += a1.w + a2.w + a3.w;
    }
    // combine the 4 groups (wave-uniform control)
    a0.x += __shfl_xor(a0.x, 16); a0.y += __shfl_xor(a0.y, 16);
    a0.z += __shfl_xor(a0.z, 16); a0.w += __shfl_xor(a0.w, 16);
    a0.x += __shfl_xor(a0.x, 32); a0.y += __shfl_xor(a0.y, 32);
    a0.z += __shfl_xor(a0.z, 32); a0.w += __shfl_xor(a0.w, 32);
    return a0;
}

// ---------------- conv body (R6-proven): out = MLP(h + sum h[src]) ----------------
// Single reloaded weight buffer; h1 in-place in sZ (same-wave safe).
// LDS = 16K(sW) + 17K(sZ) + 0.5K = 33.5 KB -> 4 blocks/CU.

__device__ __forceinline__ void conv_body(
    const float4* __restrict__ h4,
    const int* __restrict__ row_ptr,
    const int* __restrict__ colv,
    const float* __restrict__ W1, const float* __restrict__ b1,
    const float* __restrict__ W2, const float* __restrict__ b2,
    float4* __restrict__ out4,
    float (&sW)[D][D], float4 (&sZ4)[TILE][17], float* sB1, float* sB2,
    int node0)
{
    int tid = threadIdx.x;

    {
        const float4* w14 = (const float4*)W1;
        float4* s14 = (float4*)sW;
        for (int i = tid; i < D * D / 4; i += TPB) s14[i] = w14[i];
        if (tid < D) { sB1[tid] = b1[tid]; sB2[tid] = b2[tid]; }
    }

    int wave = tid >> 6, lane = tid & 63;
    int g = lane >> 4, q = lane & 15;

    for (int r = wave; r < TILE; r += (TPB / 64)) {
        int n = node0 + r;
        float4 a = gather_row(h4, row_ptr, colv, (n < NN) ? n : -1, g, q);
        if (g == 0) sZ4[r][q] = a;
    }
    __syncthreads();    // covers W1 preload + gather

    int tr = tid >> 4, tc = tid & 15;
    float* zr0 = (float*)&sZ4[tr * 2 + 0][0];
    float* zr1 = (float*)&sZ4[tr * 2 + 1][0];

    float acc[2][4];
    #pragma unroll
    for (int c = 0; c < 4; ++c) { acc[0][c] = sB1[tc * 4 + c]; acc[1][c] = sB1[tc * 4 + c]; }
    #pragma unroll 16
    for (int k = 0; k < D; ++k) {
        float z0 = zr0[k], z1 = zr1[k];
        #pragma unroll
        for (int c = 0; c < 4; ++c) {
            float w = sW[k][tc * 4 + c];
            acc[0][c] += z0 * w;
            acc[1][c] += z1 * w;
        }
    }
    {
        float4 h0, h1;
        h0.x = fmaxf(acc[0][0], 0.f); h0.y = fmaxf(acc[0][1], 0.f);
        h0.z = fmaxf(acc[0][2], 0.f); h0.w = fmaxf(acc[0][3], 0.f);
        h1.x = fmaxf(acc[1][0], 0.f); h1.y = fmaxf(acc[1][1], 0.f);
        h1.z = fmaxf(acc[1][2], 0.f); h1.w = fmaxf(acc[1][3], 0.f);
        *(float4*)&zr0[tc * 4] = h0;     // same-wave in-place, safe
        *(float4*)&zr1[tc * 4] = h1;
    }
    __syncthreads();    // all layer-1 reads of sW done

    {
        const float4* w24 = (const float4*)W2;
        float4* s24 = (float4*)sW;
        for (int i = tid; i < D * D / 4; i += TPB) s24[i] = w24[i];
    }
    __syncthreads();    // W2 visible

    #pragma unroll
    for (int c = 0; c < 4; ++c) { acc[0][c] = sB2[tc * 4 + c]; acc[1][c] = sB2[tc * 4 + c]; }
    #pragma unroll 16
    for (int k = 0; k < D; ++k) {
        float z0 = zr0[k], z1 = zr1[k];
        #pragma unroll
        for (int c = 0; c < 4; ++c) {
            float w = sW[k][tc * 4 + c];
            acc[0][c] += z0 * w;
            acc[1][c] += z1 * w;
        }
    }
    #pragma unroll
    for (int i = 0; i < 2; ++i) {
        int n = node0 + tr * 2 + i;
        if (n < NN) {
            float4 o;
            o.x = acc[i][0]; o.y = acc[i][1]; o.z = acc[i][2]; o.w = acc[i][3];
            out4[n * 16 + tc] = o;
        }
    }
}

__global__ __launch_bounds__(TPB, 8) void k_conv(
    const float4* __restrict__ h4,
    const int* __restrict__ row_ptr,
    const int* __restrict__ colv,
    const float* __restrict__ W1, const float* __restrict__ b1,
    const float* __restrict__ W2, const float* __restrict__ b2,
    float4* __restrict__ out4)
{
    __shared__ float sW[D][D];
    __shared__ float4 sZ4[TILE][17];
    __shared__ float sB1[D], sB2[D];
    conv_body(h4, row_ptr, colv, W1, b1, W2, b2, out4,
              sW, sZ4, sB1, sB2, blockIdx.x * TILE);
}

// two independent convs in one launch: blocks [0,nb) do A, [nb,2nb) do B
__global__ __launch_bounds__(TPB, 8) void k_conv_dual(
    const float4* __restrict__ hA4, const float4* __restrict__ hB4,
    const int* __restrict__ row_ptr,
    const int* __restrict__ colv,
    const float* __restrict__ W1a, const float* __restrict__ b1a,
    const float* __restrict__ W2a, const float* __restrict__ b2a,
    const float* __restrict__ W1b, const float* __restrict__ b1b,
    const float* __restrict__ W2b, const float* __restrict__ b2b,
    float4* __restrict__ outA4, float4* __restrict__ outB4, int nb)
{
    __shared__ float sW[D][D];
    __shared__ float4 sZ4[TILE][17];
    __shared__ float sB1[D], sB2[D];
    int b = blockIdx.x;
    if (b < nb) {
        conv_body(hA4, row_ptr, colv, W1a, b1a, W2a, b2a, outA4,
                  sW, sZ4, sB1, sB2, b * TILE);
    } else {
        conv_body(hB4, row_ptr, colv, W1b, b1b, W2b, b2b, outB4,
                  sW, sZ4, sB1, sB2, (b - nb) * TILE);
    }
}

// ---------------- one gather of x, three MLPs (params 0/1/2) — R6 verbatim ----------------

__global__ __launch_bounds__(TPB) void k_aggmlp3(
    const float4* __restrict__ h4,
    const int* __restrict__ row_ptr,
    const int* __restrict__ colv,
    const float* __restrict__ W1a, const float* __restrict__ b1a,
    const float* __restrict__ W2a, const float* __restrict__ b2a,
    const float* __restrict__ W1b, const float* __restrict__ b1b,
    const float* __restrict__ W2b, const float* __restrict__ b2b,
    const float* __restrict__ W1c, const float* __restrict__ b1c,
    const float* __restrict__ W2c, const float* __restrict__ b2c,
    float4* __restrict__ outA, float4* __restrict__ outB, float4* __restrict__ outC)
{
    __shared__ float sW[D][D];          // 16 KB, reloaded per layer
    __shared__ float4 sZ4[TILE][17];    // z = x + agg (preserved)
    __shared__ float4 sH4[TILE][17];    // layer-1 output
    __shared__ float sB[D];

    int tid = threadIdx.x;
    int node0 = blockIdx.x * TILE;

    int wave = tid >> 6, lane = tid & 63;
    int g = lane >> 4, q = lane & 15;

    for (int r = wave; r < TILE; r += (TPB / 64)) {
        int n = node0 + r;
        float4 a = gather_row(h4, row_ptr, colv, (n < NN) ? n : -1, g, q);
        if (g == 0) sZ4[r][q] = a;
    }

    int tr = tid >> 4, tc = tid & 15;
    float* zr0 = (float*)&sZ4[tr * 2 + 0][0];
    float* zr1 = (float*)&sZ4[tr * 2 + 1][0];
    float* hr0 = (float*)&sH4[tr * 2 + 0][0];
    float* hr1 = (float*)&sH4[tr * 2 + 1][0];

    #pragma unroll 1
    for (int m = 0; m < 3; ++m) {
        const float* W1 = (m == 0) ? W1a : (m == 1) ? W1b : W1c;
        const float* B1 = (m == 0) ? b1a : (m == 1) ? b1b : b1c;
        const float* W2 = (m == 0) ? W2a : (m == 1) ? W2b : W2c;
        const float* B2 = (m == 0) ? b2a : (m == 1) ? b2b : b2c;
        float4* out4 = (m == 0) ? outA : (m == 1) ? outB : outC;

        // load W1, b1 (first iteration's sync also covers the gather)
        {
            const float4* w4 = (const float4*)W1;
            float4* s4 = (float4*)sW;
            for (int i = tid; i < D * D / 4; i += TPB) s4[i] = w4[i];
            if (tid < D) sB[tid] = B1[tid];
        }
        __syncthreads();

        float acc[2][4];
        #pragma unroll
        for (int c = 0; c < 4; ++c) { acc[0][c] = sB[tc * 4 + c]; acc[1][c] = sB[tc * 4 + c]; }
        #pragma unroll 16
        for (int k = 0; k < D; ++k) {
            float z0 = zr0[k], z1 = zr1[k];
            #pragma unroll
            for (int c = 0; c < 4; ++c) {
                float w = sW[k][tc * 4 + c];
                acc[0][c] += z0 * w;
                acc[1][c] += z1 * w;
            }
        }
        {
            float4 h0, h1;
            h0.x = fmaxf(acc[0][0], 0.f); h0.y = fmaxf(acc[0][1], 0.f);
            h0.z = fmaxf(acc[0][2], 0.f); h0.w = fmaxf(acc[0][3], 0.f);
            h1.x = fmaxf(acc[1][0], 0.f); h1.y = fmaxf(acc[1][1], 0.f);
            h1.z = fmaxf(acc[1][2], 0.f); h1.w = fmaxf(acc[1][3], 0.f);
            *(float4*)&hr0[tc * 4] = h0;
            *(float4*)&hr1[tc * 4] = h1;
        }
        __syncthreads();

        // load W2, b2
        {
            const float4* w4 = (const float4*)W2;
            float4* s4 = (float4*)sW;
            for (int i = tid; i < D * D / 4; i += TPB) s4[i] = w4[i];
            if (tid < D) sB[tid] = B2[tid];
        }
        __syncthreads();

        #pragma unroll
        for (int c = 0; c < 4; ++c) { acc[0][c] = sB[tc * 4 + c]; acc[1][c] = sB[tc * 4 + c]; }
        #pragma unroll 16
        for (int k = 0; k < D; ++k) {
            float h0 = hr0[k], h1 = hr1[k];
            #pragma unroll
            for (int c = 0; c < 4; ++c) {
                float w = sW[k][tc * 4 + c];
                acc[0][c] += h0 * w;
                acc[1][c] += h1 * w;
            }
        }
        #pragma unroll
        for (int i = 0; i < 2; ++i) {
            int n = node0 + tr * 2 + i;
            if (n < NN) {
                float4 o;
                o.x = acc[i][0]; o.y = acc[i][1]; o.z = acc[i][2]; o.w = acc[i][3];
                out4[n * 16 + tc] = o;
            }
        }
        __syncthreads();   // protect sW/sB before next MLP's load
    }
}

// ---------------- final projection, chunked: out = bo + sum_c Hc @ Wo[c] ----------------

__global__ __launch_bounds__(TPB, 8) void k_final(
    const float4* __restrict__ H0, const float4* __restrict__ H1,
    const float4* __restrict__ H2,
    const float* __restrict__ Wo, const float* __restrict__ bo,
    float4* __restrict__ out4)
{
    __shared__ float sW[D][D];         // one 64x64 chunk of Wo at a time
    __shared__ float4 sY4[TILE][17];   // one 64-feature slice of [H0|H1|H2]
    __shared__ float sB[D];

    int tid = threadIdx.x;
    int node0 = blockIdx.x * TILE;
    int tr = tid >> 4, tc = tid & 15;
    const float* yr0 = (const float*)&sY4[tr * 2 + 0][0];
    const float* yr1 = (const float*)&sY4[tr * 2 + 1][0];

    float accO[2][4];

    #pragma unroll 1
    for (int m = 0; m < 3; ++m) {
        const float4* Hc = (m == 0) ? H0 : (m == 1) ? H1 : H2;
        {
            const float4* w4 = (const float4*)(Wo + m * 64 * D);
            float4* s4 = (float4*)sW;
            for (int i = tid; i < D * D / 4; i += TPB) s4[i] = w4[i];
            if (m == 0 && tid < D) sB[tid] = bo[tid];
        }
        for (int i = tid; i < TILE * 16; i += TPB) {
            int r = i >> 4, qq = i & 15;
            int n = node0 + r;
            sY4[r][qq] = (n < NN) ? Hc[n * 16 + qq] : make_float4(0.f, 0.f, 0.f, 0.f);
        }
        __syncthreads();

        if (m == 0) {
            #pragma unroll
            for (int c = 0; c < 4; ++c) { accO[0][c] = sB[tc * 4 + c]; accO[1][c] = sB[tc * 4 + c]; }
        }
        #pragma unroll 16
        for (int k = 0; k < D; ++k) {
            float z0 = yr0[k], z1 = yr1[k];
            #pragma unroll
            for (int c = 0; c < 4; ++c) {
                float w = sW[k][tc * 4 + c];
                accO[0][c] += z0 * w;
                accO[1][c] += z1 * w;
            }
        }
        __syncthreads();   // before next chunk overwrites sW/sY
    }

    #pragma unroll
    for (int i = 0; i < 2; ++i) {
        int n = node0 + tr * 2 + i;
        if (n < NN) {
            float4 o;
            o.x = accO[i][0]; o.y = accO[i][1]; o.z = accO[i][2]; o.w = accO[i][3];
            out4[n * 16 + tc] = o;
        }
    }
}

// ---------------- launch ----------------

extern "C" void kernel_launch(void* const* d_in, const int* in_sizes, int n_in,
                              void* d_out, int out_size, void* d_ws, size_t ws_size,
                              hipStream_t stream) {
    const float* x    = (const float*)d_in[0];
    const int*   ei   = (const int*)d_in[1];   // [2, NE] int32
    const float* W1_0 = (const float*)d_in[2];
    const float* b1_0 = (const float*)d_in[3];
    const float* W2_0 = (const float*)d_in[4];
    const float* b2_0 = (const float*)d_in[5];
    const float* W1_1 = (const float*)d_in[6];
    const float* b1_1 = (const float*)d_in[7];
    const float* W2_1 = (const float*)d_in[8];
    const float* b2_1 = (const float*)d_in[9];
    const float* W1_2 = (const float*)d_in[10];
    const float* b1_2 = (const float*)d_in[11];
    const float* W2_2 = (const float*)d_in[12];
    const float* b2_2 = (const float*)d_in[13];
    const float* Wo   = (const float*)d_in[14];
    const float* bo   = (const float*)d_in[15];
    float4* out = (float4*)d_out;

    char* ws = (char*)d_ws;
    int* deg     = (int*)(ws + 0);
    int* cursor  = (int*)(ws + 200704);
    int* row_ptr = (int*)(ws + 401408);
    int* colv    = (int*)(ws + 602112);
    int* bsum    = (int*)(ws + 3802112);
    float* fbase = (float*)(ws + 3804160);
    float4* H0  = (float4*)(fbase);
    float4* H1  = (float4*)(fbase + 3200000);
    float4* tB  = (float4*)(fbase + 6400000);   // later reused as H2
    float4* tC2 = (float4*)(fbase + 9600000);
    const float4* x4 = (const float4*)x;

    // CSR build
    hipMemsetAsync(deg, 0, NN * sizeof(int), stream);
    k_count<<<(NE + 255) / 256, 256, 0, stream>>>(ei, deg);
    k_bsum <<<NBLK, 256, 0, stream>>>(deg, bsum);
    k_scan2<<<NBLK, 256, 0, stream>>>(deg, bsum, row_ptr, cursor);
    k_fill <<<(NE + 255) / 256, 256, 0, stream>>>(ei, cursor, colv);

    int nb = (NN + TILE - 1) / TILE;  // 782

    // one gather of x, three MLPs: H0 = f0(x), tB = f1(x), out = f2(x)
    k_aggmlp3<<<nb, TPB, 0, stream>>>(x4, row_ptr, colv,
                                      W1_0, b1_0, W2_0, b2_0,
                                      W1_1, b1_1, W2_1, b2_1,
                                      W1_2, b1_2, W2_2, b2_2,
                                      H0, tB, out);

    // independent pair in one launch: H1 = f1(tB), tC2 = f2(out)
    k_conv_dual<<<2 * nb, TPB, 0, stream>>>(
        (const float4*)tB, (const float4*)out, row_ptr, colv,
        W1_1, b1_1, W2_1, b2_1,
        W1_2, b1_2, W2_2, b2_2,
        H1, tC2, nb);

    // hop-3 tail: H2 (tB reused) = f2(tC2)
    k_conv<<<nb, TPB, 0, stream>>>((const float4*)tC2, row_ptr, colv,
                                   W1_2, b1_2, W2_2, b2_2, tB);

    // final projection
    k_final<<<nb, TPB, 0, stream>>>((const float4*)H0, (const float4*)H1, (const float4*)tB,
                                    Wo, bo, out);
}